// Round 16
// baseline (240.233 us; speedup 1.0000x reference)
//
#include <hip/hip_runtime.h>

// B=65536, Q=128, S=8, U=32
// out[b,q] = b2[q] + sum_u elu(b1[q,u] + sum_s x[b,q,s]*W1[q,s,u]) * W2[q,u]
//
// R16: barrier-free wave-private producer-consumer.
//  - 1-wave blocks (64 thr). Each wave owns 32 rows x 32 q; chunks of 2 q.
//  - global_load_lds DMA (2 instrs/chunk) into a PRIVATE 3-buffer LDS ring;
//    sync via counted s_waitcnt vmcnt(4) only (DMA depth 2 stays in flight).
//  - LDS layout [q][s-half][row*16B]: consume = 2x ds_read_b128 contiguous
//    512B -> conflict-free (R15's 1M conflicts came from bl*32 stride).
//  - hi lanes (k=8..15 pad) broadcast-read lo addresses + zmask (free).
//  - no __syncthreads anywhere: waves fully phase-decorrelated (T3/T4).
#define Q    128
#define S    8
#define U    32
#define ROWS 32
#define QW   32            // q per wave
#define NCHK 16            // chunks of 2 q
#define CBUF 2048          // bytes per chunk buffer (2q x 32row x 32B)
#define NBUF 3

typedef __attribute__((ext_vector_type(8)))  __bf16 bf16x8;
typedef __attribute__((ext_vector_type(16))) float  f32x16;
typedef __attribute__((ext_vector_type(2)))  float  f32x2;

__device__ inline unsigned short f2bf(float f) {   // RTN f32->bf16 (prep only)
    unsigned int u = __float_as_uint(f);
    u += 0x7FFF + ((u >> 16) & 1);
    return (unsigned short)(u >> 16);
}

__device__ inline unsigned int cvt_pk_bf16(float lo, float hi) {
    unsigned int r;
    asm("v_cvt_pk_bf16_f32 %0, %1, %2" : "=v"(r) : "v"(lo), "v"(hi));
    return r;
}

// ---- prep: W1T[q][u][s] bf16 ; b1F=(b1+1), w2F in C-reg order ; b2F=b2-sum(W2)
__global__ void prep_kernel(const float* __restrict__ W1, const float* __restrict__ b1,
                            const float* __restrict__ W2, const float* __restrict__ b2,
                            unsigned short* __restrict__ W1T,
                            float* __restrict__ b1F, float* __restrict__ w2F,
                            float* __restrict__ b2F)
{
    const int q = blockIdx.x, t = threadIdx.x;     // 128 blocks x 256 threads
    const int u = t & 31, s = t >> 5;
    W1T[(q * 32 + u) * 8 + s] = f2bf(W1[(q * 8 + s) * 32 + u]);
    if (t < 32) {
        int reg = t & 15, hh = t >> 4;
        int uu  = (reg & 3) + 8 * (reg >> 2) + 4 * hh;   // verified C/D row map
        b1F[(q * 2 + hh) * 16 + reg] = b1[q * 32 + uu] + 1.0f;
        w2F[(q * 2 + hh) * 16 + reg] = W2[q * 32 + uu];
    }
    if (t == 0) {
        float sw = 0.f;
        for (int uu = 0; uu < 32; ++uu) sw += W2[q * 32 + uu];
        b2F[q] = b2[q] - sw;
    }
}

__global__ __launch_bounds__(64, 4)   // 1 wave/block; VGPR budget 128
void divenc_pc(const float* __restrict__ x,
               const unsigned short* __restrict__ W1T,
               const float* __restrict__ b1F,
               const float* __restrict__ w2F,
               const float* __restrict__ b2F,
               float* __restrict__ out, int B)
{
    __shared__ __align__(16) unsigned char xs[NBUF * CBUF];   // 6 KB

    const int t  = threadIdx.x;          // = lane
    const int bl = t & 31;
    const int h  = t >> 5;
    const bool lo = (t < 32);
    const unsigned int zmask = lo ? 0xFFFFFFFFu : 0u;

    const int bid   = blockIdx.x;
    const int rbase = (bid >> 2) * ROWS;
    const int q0b   = (bid & 3) * QW;

    // per-lane DMA source: row = bl, s-half = h (matches linear LDS lane order:
    // dst slot L*16 <-> [part=L>>5][row=L&31] of layout [q][part*512][row*16])
    const char* xsrc = (const char*)x
        + (size_t)(rbase + bl) * (Q * S * 4)
        + (size_t)q0b * 32 + h * 16;

    const f32x2 l2e2  = 1.44269504088896f;
    const f32x2 nl2e2 = -1.44269504088896f;
    const f32x2 zero2 = 0.0f;

#define DMA(CH, BUF) {                                                               \
    const char* s_ = xsrc + (CH) * 64;           /* q_local = 2*CH, 2*CH+1 */        \
    unsigned char* d_ = xs + (BUF) * CBUF;                                           \
    __builtin_amdgcn_global_load_lds(                                                \
        (const __attribute__((address_space(1))) unsigned int*)s_,                   \
        (__attribute__((address_space(3))) unsigned int*)d_, 16, 0, 0);              \
    __builtin_amdgcn_global_load_lds(                                                \
        (const __attribute__((address_space(1))) unsigned int*)(s_ + 32),            \
        (__attribute__((address_space(3))) unsigned int*)(d_ + 1024), 16, 0, 0); }

#define EL2(CC, J, ACC) {                                                            \
    f32x2 v_; v_.x = CC[2*(J)]; v_.y = CC[2*(J)+1];                                  \
    f32x2 w2v; w2v.x = wr[2*(J)]; w2v.y = wr[2*(J)+1];                               \
    f32x2 f_ = __builtin_elementwise_fma(v_, l2e2, nl2e2);                           \
    f_ = __builtin_elementwise_min(f_, zero2);                                       \
    f32x2 e_; e_.x = __builtin_amdgcn_exp2f(f_.x);                                   \
    e_.y = __builtin_amdgcn_exp2f(f_.y);                                             \
    f32x2 r_ = __builtin_elementwise_max(v_, e_);                                    \
    ACC = __builtin_elementwise_fma(r_, w2v, ACC); }

#define CONSUME(CH, BUF, QI) {                                                       \
    const int q_ = q0b + (CH) * 2 + (QI);                                            \
    const unsigned char* b_ = xs + (BUF) * CBUF + (QI) * 1024 + bl * 16;             \
    float4 p0 = *(const float4*)b_;              /* s0..3 (hi lanes: broadcast) */   \
    float4 p1 = *(const float4*)(b_ + 512);      /* s4..7 */                         \
    uint4 bx;                                                                        \
    bx.x = cvt_pk_bf16(p0.x, p0.y) & zmask;                                          \
    bx.y = cvt_pk_bf16(p0.z, p0.w) & zmask;                                          \
    bx.z = cvt_pk_bf16(p1.x, p1.y) & zmask;                                          \
    bx.w = cvt_pk_bf16(p1.z, p1.w) & zmask;                                          \
    uint4  ax  = *(const uint4*)(W1T + ((size_t)q_ * 32 + bl) * 8);                  \
    f32x16 cin = *(const f32x16*)(b1F + ((size_t)q_ * 2 + h) * 16);                  \
    f32x16 cc  = __builtin_amdgcn_mfma_f32_32x32x16_bf16(                            \
        __builtin_bit_cast(bf16x8, ax), __builtin_bit_cast(bf16x8, bx),              \
        cin, 0, 0, 0);                                                               \
    f32x16 wr  = *(const f32x16*)(w2F + ((size_t)q_ * 2 + h) * 16);                  \
    const float b2v = b2F[q_];                                                       \
    f32x2 acc = 0.0f;                                                                \
    EL2(cc, 0, acc) EL2(cc, 1, acc) EL2(cc, 2, acc) EL2(cc, 3, acc)                  \
    EL2(cc, 4, acc) EL2(cc, 5, acc) EL2(cc, 6, acc) EL2(cc, 7, acc)                  \
    float a0 = acc.x + acc.y;                                                        \
    a0 += __shfl_xor(a0, 32);                    /* combine u-halves */              \
    if (lo) out[(size_t)(rbase + bl) * Q + q_] = a0 + b2v; }

    // ---- pipeline: depth-2 DMA prefetch, counted vmcnt, no barriers ----
    DMA(0, 0) DMA(1, 1)
    int rb = 0, nb = 2;
    #pragma unroll 1
    for (int ch = 0; ch < NCHK; ++ch) {
        if (ch + 2 < NCHK) DMA(ch + 2, nb)
        __builtin_amdgcn_sched_barrier(0);
        // all vmem older than the 4 newest (= DMA ch+1, ch+2) are drained
        // => DMA(ch) complete. Never drains the in-flight prefetches.
        asm volatile("s_waitcnt vmcnt(4)" ::: "memory");
        __builtin_amdgcn_sched_barrier(0);
        CONSUME(ch, rb, 0)
        CONSUME(ch, rb, 1)
        rb = (rb == NBUF - 1) ? 0 : rb + 1;
        nb = (nb == NBUF - 1) ? 0 : nb + 1;
    }
#undef DMA
#undef EL2
#undef CONSUME
}

extern "C" void kernel_launch(void* const* d_in, const int* in_sizes, int n_in,
                              void* d_out, int out_size, void* d_ws, size_t ws_size,
                              hipStream_t stream) {
    const float* x  = (const float*)d_in[0];
    const float* W1 = (const float*)d_in[1];
    const float* b1 = (const float*)d_in[2];
    const float* W2 = (const float*)d_in[3];
    const float* b2 = (const float*)d_in[4];
    float* out = (float*)d_out;

    unsigned short* W1T = (unsigned short*)d_ws;                 // 64 KB
    float*          b1F = (float*)((char*)d_ws + 65536);         // 16 KB
    float*          w2F = (float*)((char*)d_ws + 81920);         // 16 KB
    float*          b2F = (float*)((char*)d_ws + 98304);         // 512 B

    const int B = in_sizes[0] / (Q * S);
    const int nblocks = (B / ROWS) * (Q / QW);   // 8192 one-wave blocks

    hipLaunchKernelGGL(prep_kernel, dim3(Q), dim3(256), 0, stream,
                       W1, b1, W2, b2, W1T, b1F, w2F, b2F);
    hipLaunchKernelGGL(divenc_pc, dim3(nblocks), dim3(64), 0, stream,
                       x, W1T, b1F, w2F, b2F, out, B);
}

// Round 17
// 109.694 us; speedup vs baseline: 2.1900x; 2.1900x over previous
//
#include <hip/hip_runtime.h>

// B=65536, Q=128, S=8, U=32
// out[b,q] = b2[q] + sum_u elu(b1[q,u] + sum_s x[b,q,s]*W1[q,s,u]) * W2[q,u]
//
// R17 = R9 (112us anchor) + coalesced output stores:
//  per-qi results go to a 64x(stride20) LDS os-tile (lane=row scatter was the
//  last uncoalesced access: 32 lines x 4B per store instr); after the chunk's
//  4 qi, one barrier, then each thread stores one float4 = 16 consecutive q
//  of one row (64B/lane dense, 8x fewer line-touches). 2 barriers/chunk kept.
#define Q    128
#define S    8
#define U    32
#define QCH  16
#define NCH  (Q / QCH)
#define ROWS 64
#define WQ   4
#define RSTRIDE 272
#define ZOFF (ROWS * RSTRIDE)
#define OSS  20             // os stride (floats): 80B, 16B-aligned rows

typedef __attribute__((ext_vector_type(8)))  __bf16 bf16x8;
typedef __attribute__((ext_vector_type(16))) float  f32x16;
typedef __attribute__((ext_vector_type(2)))  float  f32x2;

__device__ inline unsigned short f2bf(float f) {   // RTN f32->bf16 (prep only)
    unsigned int u = __float_as_uint(f);
    u += 0x7FFF + ((u >> 16) & 1);
    return (unsigned short)(u >> 16);
}

__device__ inline unsigned int cvt_pk_bf16(float lo, float hi) {
    unsigned int r;
    asm("v_cvt_pk_bf16_f32 %0, %1, %2" : "=v"(r) : "v"(lo), "v"(hi));
    return r;
}

// ---- prep: W1T[q][u][s] bf16 ; b1F=(b1+1), w2F in C-reg order ; b2F=b2-sum(W2)
__global__ void prep_kernel(const float* __restrict__ W1, const float* __restrict__ b1,
                            const float* __restrict__ W2, const float* __restrict__ b2,
                            unsigned short* __restrict__ W1T,
                            float* __restrict__ b1F, float* __restrict__ w2F,
                            float* __restrict__ b2F)
{
    const int q = blockIdx.x, t = threadIdx.x;     // 128 blocks x 256 threads
    const int u = t & 31, s = t >> 5;
    W1T[(q * 32 + u) * 8 + s] = f2bf(W1[(q * 8 + s) * 32 + u]);
    if (t < 32) {
        int reg = t & 15, hh = t >> 4;
        int uu  = (reg & 3) + 8 * (reg >> 2) + 4 * hh;   // verified C/D row map
        b1F[(q * 2 + hh) * 16 + reg] = b1[q * 32 + uu] + 1.0f;
        w2F[(q * 2 + hh) * 16 + reg] = W2[q * 32 + uu];
    }
    if (t == 0) {
        float sw = 0.f;
        for (int uu = 0; uu < 32; ++uu) sw += W2[q * 32 + uu];
        b2F[q] = b2[q] - sw;
    }
}

__global__ __launch_bounds__(256, 4)   // VGPR budget 128
void divenc_mfma(const float* __restrict__ x,
                 const unsigned short* __restrict__ W1T,
                 const float* __restrict__ b1F,
                 const float* __restrict__ w2F,
                 const float* __restrict__ b2F,
                 float* __restrict__ out, int B)
{
    __shared__ __align__(16) unsigned char xs[ROWS * RSTRIDE + 16];  // ~17.4 KB
    __shared__ __align__(16) float os[ROWS * OSS];                    // 5 KB

    const int t     = threadIdx.x;
    const int lane  = t & 63;
    const int wv    = __builtin_amdgcn_readfirstlane(t >> 6);
    const int rbase = blockIdx.x * ROWS;
    const int rmax  = B - 1;
    const int bl    = lane & 31;
    const int h     = lane >> 5;
    const bool lo   = (lane < 32);

    if (t == 0) *(uint4*)(xs + ZOFF) = uint4{0, 0, 0, 0};   // zero page

    const f32x2 l2e2  = 1.44269504088896f;
    const f32x2 nl2e2 = -1.44269504088896f;
    const f32x2 zero2 = 0.0f;

#define STAGE(Q0) {                                                                  \
    _Pragma("unroll")                                                                \
    for (int k = 0; k < 4; ++k) {                                                    \
        int idx = t + k * 256;                                                       \
        int row = idx >> 4, qr = idx & 15;                                           \
        int r = rbase + row; if (r > rmax) r = rmax;                                 \
        const float4* p = (const float4*)(x + (size_t)r * (Q * S)                    \
                                            + (size_t)((Q0) + qr) * S);              \
        float4 a = p[0], b = p[1];                                                   \
        uint4 w;                                                                     \
        w.x = cvt_pk_bf16(a.x, a.y); w.y = cvt_pk_bf16(a.z, a.w);                    \
        w.z = cvt_pk_bf16(b.x, b.y); w.w = cvt_pk_bf16(b.z, b.w);                    \
        *(uint4*)(xs + row * RSTRIDE + qr * 16) = w; } }

    STAGE(0)                                  // prologue: chunk 0

    #pragma unroll 1
    for (int ch = 0; ch < NCH; ++ch) {
        const int q0 = ch * QCH;
        __syncthreads();                      // xs[ch] staged; os free

        // ---- compute: wave wv handles q = q0 + wv*4 + qi, 2 row-tiles each ----
        #pragma unroll 1
        for (int qi = 0; qi < WQ; ++qi) {
            const int qr = wv * WQ + qi;      // uniform per wave
            const int q  = q0 + qr;

            const int xoff = bl * RSTRIDE + qr * 16;
            uint4 bx0 = *(const uint4*)(xs + (lo ? xoff                : ZOFF));
            uint4 bx1 = *(const uint4*)(xs + (lo ? xoff + 32 * RSTRIDE : ZOFF));

            uint4 ax = *(const uint4*)(W1T + ((size_t)q * 32 + bl) * 8);
            f32x16 cin = *(const f32x16*)(b1F + ((size_t)q * 2 + h) * 16);

            f32x16 cc0 = __builtin_amdgcn_mfma_f32_32x32x16_bf16(
                __builtin_bit_cast(bf16x8, ax), __builtin_bit_cast(bf16x8, bx0),
                cin, 0, 0, 0);
            f32x16 cc1 = __builtin_amdgcn_mfma_f32_32x32x16_bf16(
                __builtin_bit_cast(bf16x8, ax), __builtin_bit_cast(bf16x8, bx1),
                cin, 0, 0, 0);

            f32x16 wr = *(const f32x16*)(w2F + ((size_t)q * 2 + h) * 16);
            const float b2v = b2F[q];

            // ---- 5-op ELU+1: r = max(v', exp2(min(v'*log2e - log2e, 0))) ----
#define EL2(CC, J, ACC) {                                                            \
        f32x2 v_; v_.x = CC[2*(J)]; v_.y = CC[2*(J)+1];                              \
        f32x2 w2v; w2v.x = wr[2*(J)]; w2v.y = wr[2*(J)+1];                           \
        f32x2 f_ = __builtin_elementwise_fma(v_, l2e2, nl2e2);                       \
        f_ = __builtin_elementwise_min(f_, zero2);                                   \
        f32x2 e_; e_.x = __builtin_amdgcn_exp2f(f_.x);                               \
        e_.y = __builtin_amdgcn_exp2f(f_.y);                                         \
        f32x2 r_ = __builtin_elementwise_max(v_, e_);                                \
        ACC = __builtin_elementwise_fma(r_, w2v, ACC); }

            f32x2 acc0 = 0.0f, acc1 = 0.0f;
            EL2(cc0, 0, acc0) EL2(cc0, 1, acc0) EL2(cc0, 2, acc0) EL2(cc0, 3, acc0)
            EL2(cc0, 4, acc0) EL2(cc0, 5, acc0) EL2(cc0, 6, acc0) EL2(cc0, 7, acc0)
            EL2(cc1, 0, acc1) EL2(cc1, 1, acc1) EL2(cc1, 2, acc1) EL2(cc1, 3, acc1)
            EL2(cc1, 4, acc1) EL2(cc1, 5, acc1) EL2(cc1, 6, acc1) EL2(cc1, 7, acc1)
#undef EL2

            float a0 = acc0.x + acc0.y;
            float a1 = acc1.x + acc1.y;
            a0 += __shfl_xor(a0, 32);         // combine u-halves
            a1 += __shfl_xor(a1, 32);

            if (lo) {                         // results -> os tile (conflict-light)
                os[bl * OSS + qr]        = a0 + b2v;
                os[(bl + 32) * OSS + qr] = a1 + b2v;
            }
        }
        __syncthreads();                      // os complete; xs consumed

        // ---- coalesced store: each thread 1 float4 = 16B of one row ----
        {
            int row = t >> 2, c = t & 3;
            float4 o = *(const float4*)&os[row * OSS + c * 4];
            int r = rbase + row;
            if (r < B)
                *(float4*)(out + (size_t)r * Q + q0 + c * 4) = o;
        }

        if (ch + 1 < NCH) STAGE(q0 + QCH)     // stage next (xs free; next barrier protects)
    }
#undef STAGE
}

extern "C" void kernel_launch(void* const* d_in, const int* in_sizes, int n_in,
                              void* d_out, int out_size, void* d_ws, size_t ws_size,
                              hipStream_t stream) {
    const float* x  = (const float*)d_in[0];
    const float* W1 = (const float*)d_in[1];
    const float* b1 = (const float*)d_in[2];
    const float* W2 = (const float*)d_in[3];
    const float* b2 = (const float*)d_in[4];
    float* out = (float*)d_out;

    unsigned short* W1T = (unsigned short*)d_ws;                 // 64 KB
    float*          b1F = (float*)((char*)d_ws + 65536);         // 16 KB
    float*          w2F = (float*)((char*)d_ws + 81920);         // 16 KB
    float*          b2F = (float*)((char*)d_ws + 98304);         // 512 B

    const int B = in_sizes[0] / (Q * S);

    hipLaunchKernelGGL(prep_kernel, dim3(Q), dim3(256), 0, stream,
                       W1, b1, W2, b2, W1T, b1F, w2F, b2F);
    hipLaunchKernelGGL(divenc_mfma, dim3((B + ROWS - 1) / ROWS), dim3(256), 0, stream,
                       x, W1T, b1F, w2F, b2F, out, B);
}

// Round 18
// 95.411 us; speedup vs baseline: 2.5179x; 1.1497x over previous
//
#include <hip/hip_runtime.h>

// B=65536, Q=128, S=8, U=32
// out[b,q] = b2[q] + sum_u elu(b1[q,u] + sum_s x[b,q,s]*W1[q,s,u]) * W2[q,u]
//
// R18: weights-in-registers / rows-deep blocks (TA-pipe theory).
//  R9/R17 reloaded every q's weights at every visit: ~1.2M VMEM instr/pass of
//  weight loads saturating the per-CU TA pipe (~30-45us serial). Invert the
//  block aspect: 8 q x 1024 rows per block; each wave owns 2 q PERMANENTLY
//  (ax/cin/wr/b2 = 74 VGPR loaded once), 16 row-tiles of 64 staged/computed
//  with zero weight VMEM. Staging/LDS/store patterns byte-copied from the
//  measured-conflict-free R9/R17 kernels.
#define Q    128
#define S    8
#define U    32
#define QW   8              // q per block
#define TROWS 64            // rows per tile
#define RPB  1024           // rows per block
#define NTILE (RPB / TROWS) // 16
#define RSTRIDE 272         // xs row stride bytes (R9-verified conflict-free)
#define ZOFF (TROWS * RSTRIDE)
#define OSS  20             // os row stride floats (R17 pattern)

typedef __attribute__((ext_vector_type(8)))  __bf16 bf16x8;
typedef __attribute__((ext_vector_type(16))) float  f32x16;
typedef __attribute__((ext_vector_type(2)))  float  f32x2;

__device__ inline unsigned short f2bf(float f) {   // RTN f32->bf16 (prep only)
    unsigned int u = __float_as_uint(f);
    u += 0x7FFF + ((u >> 16) & 1);
    return (unsigned short)(u >> 16);
}

__device__ inline unsigned int cvt_pk_bf16(float lo, float hi) {
    unsigned int r;
    asm("v_cvt_pk_bf16_f32 %0, %1, %2" : "=v"(r) : "v"(lo), "v"(hi));
    return r;
}

// ---- prep: W1T[q][u][s] bf16 ; b1F=(b1+1), w2F in C-reg order ; b2F=b2-sum(W2)
__global__ void prep_kernel(const float* __restrict__ W1, const float* __restrict__ b1,
                            const float* __restrict__ W2, const float* __restrict__ b2,
                            unsigned short* __restrict__ W1T,
                            float* __restrict__ b1F, float* __restrict__ w2F,
                            float* __restrict__ b2F)
{
    const int q = blockIdx.x, t = threadIdx.x;     // 128 blocks x 256 threads
    const int u = t & 31, s = t >> 5;
    W1T[(q * 32 + u) * 8 + s] = f2bf(W1[(q * 8 + s) * 32 + u]);
    if (t < 32) {
        int reg = t & 15, hh = t >> 4;
        int uu  = (reg & 3) + 8 * (reg >> 2) + 4 * hh;   // verified C/D row map
        b1F[(q * 2 + hh) * 16 + reg] = b1[q * 32 + uu] + 1.0f;
        w2F[(q * 2 + hh) * 16 + reg] = W2[q * 32 + uu];
    }
    if (t == 0) {
        float sw = 0.f;
        for (int uu = 0; uu < 32; ++uu) sw += W2[q * 32 + uu];
        b2F[q] = b2[q] - sw;
    }
}

__global__ __launch_bounds__(256)
__attribute__((amdgpu_waves_per_eu(3, 4)))   // budget ~170: resident weights must not spill
void divenc_wreg(const float* __restrict__ x,
                 const unsigned short* __restrict__ W1T,
                 const float* __restrict__ b1F,
                 const float* __restrict__ w2F,
                 const float* __restrict__ b2F,
                 float* __restrict__ out, int B)
{
    __shared__ __align__(16) unsigned char xs[TROWS * RSTRIDE + 16];  // 17.4 KB
    __shared__ __align__(16) float os[TROWS * OSS];                    // 5 KB

    const int t    = threadIdx.x;
    const int lane = t & 63;
    const int wv   = __builtin_amdgcn_readfirstlane(t >> 6);
    const int bl   = lane & 31;
    const int h    = lane >> 5;
    const bool lo  = (lane < 32);

    const int bid   = blockIdx.x;
    const int qb    = (bid & 15) * QW;
    const int rbase = (bid >> 4) * RPB;
    const int rmax  = B - 1;

    if (t == 0) *(uint4*)(xs + ZOFF) = uint4{0, 0, 0, 0};   // zero page

    // ---- resident weights: wave wv owns qA, qB for the whole block ----
    const int qA = qb + wv * 2, qB = qA + 1;
    const uint4  axA  = *(const uint4*)(W1T + ((size_t)qA * 32 + bl) * 8);
    const uint4  axB  = *(const uint4*)(W1T + ((size_t)qB * 32 + bl) * 8);
    const f32x16 cinA = *(const f32x16*)(b1F + ((size_t)qA * 2 + h) * 16);
    const f32x16 cinB = *(const f32x16*)(b1F + ((size_t)qB * 2 + h) * 16);
    const f32x16 wrA  = *(const f32x16*)(w2F + ((size_t)qA * 2 + h) * 16);
    const f32x16 wrB  = *(const f32x16*)(w2F + ((size_t)qB * 2 + h) * 16);
    const float  b2A  = b2F[qA], b2B = b2F[qB];

    const f32x2 l2e2  = 1.44269504088896f;
    const f32x2 nl2e2 = -1.44269504088896f;
    const f32x2 zero2 = 0.0f;

#define STAGE(T) {                                                                   \
    _Pragma("unroll")                                                                \
    for (int k = 0; k < 2; ++k) {                                                    \
        int unit = t + k * 256;               /* 512 units = 64 rows x 8 q */        \
        int row = unit >> 3, qr = unit & 7;                                          \
        int r = rbase + (T) * TROWS + row; if (r > rmax) r = rmax;                   \
        const float4* p = (const float4*)(x + (size_t)r * (Q * S)                    \
                                            + (size_t)(qb + qr) * S);                \
        float4 a = p[0], b = p[1];                                                   \
        uint4 w;                                                                     \
        w.x = cvt_pk_bf16(a.x, a.y); w.y = cvt_pk_bf16(a.z, a.w);                    \
        w.z = cvt_pk_bf16(b.x, b.y); w.w = cvt_pk_bf16(b.z, b.w);                    \
        *(uint4*)(xs + row * RSTRIDE + qr * 16) = w; } }

#define EL2(CC, J, WR, ACC) {                                                        \
    f32x2 v_; v_.x = CC[2*(J)]; v_.y = CC[2*(J)+1];                                  \
    f32x2 w2v; w2v.x = WR[2*(J)]; w2v.y = WR[2*(J)+1];                               \
    f32x2 f_ = __builtin_elementwise_fma(v_, l2e2, nl2e2);                           \
    f_ = __builtin_elementwise_min(f_, zero2);                                       \
    f32x2 e_; e_.x = __builtin_amdgcn_exp2f(f_.x);                                   \
    e_.y = __builtin_amdgcn_exp2f(f_.y);                                             \
    f32x2 r_ = __builtin_elementwise_max(v_, e_);                                    \
    ACC = __builtin_elementwise_fma(r_, w2v, ACC); }

#define COMP(AX, CIN, WR, B2, QR) {                                                  \
    const int xoff = bl * RSTRIDE + (QR) * 16;                                       \
    uint4 bx0 = *(const uint4*)(xs + (lo ? xoff                : ZOFF));             \
    uint4 bx1 = *(const uint4*)(xs + (lo ? xoff + 32 * RSTRIDE : ZOFF));             \
    f32x16 cc0 = __builtin_amdgcn_mfma_f32_32x32x16_bf16(                            \
        __builtin_bit_cast(bf16x8, AX), __builtin_bit_cast(bf16x8, bx0),             \
        CIN, 0, 0, 0);                                                               \
    f32x16 cc1 = __builtin_amdgcn_mfma_f32_32x32x16_bf16(                            \
        __builtin_bit_cast(bf16x8, AX), __builtin_bit_cast(bf16x8, bx1),             \
        CIN, 0, 0, 0);                                                               \
    f32x2 acc0 = 0.0f, acc1 = 0.0f;                                                  \
    EL2(cc0, 0, WR, acc0) EL2(cc0, 1, WR, acc0) EL2(cc0, 2, WR, acc0)                \
    EL2(cc0, 3, WR, acc0) EL2(cc0, 4, WR, acc0) EL2(cc0, 5, WR, acc0)                \
    EL2(cc0, 6, WR, acc0) EL2(cc0, 7, WR, acc0)                                      \
    EL2(cc1, 0, WR, acc1) EL2(cc1, 1, WR, acc1) EL2(cc1, 2, WR, acc1)                \
    EL2(cc1, 3, WR, acc1) EL2(cc1, 4, WR, acc1) EL2(cc1, 5, WR, acc1)                \
    EL2(cc1, 6, WR, acc1) EL2(cc1, 7, WR, acc1)                                      \
    float a0 = acc0.x + acc0.y;                                                      \
    float a1 = acc1.x + acc1.y;                                                      \
    a0 += __shfl_xor(a0, 32);                 /* combine u-halves */                 \
    a1 += __shfl_xor(a1, 32);                                                        \
    if (lo) {                                                                        \
        os[bl * OSS + (QR)]        = a0 + (B2);                                      \
        os[(bl + 32) * OSS + (QR)] = a1 + (B2);                                      \
    } }

    STAGE(0)                                  // prologue: tile 0

    #pragma unroll 1
    for (int tile = 0; tile < NTILE; ++tile) {
        __syncthreads();                      // xs[tile] staged; os free

        COMP(axA, cinA, wrA, b2A, wv * 2)     // zero weight VMEM in the loop
        COMP(axB, cinB, wrB, b2B, wv * 2 + 1)

        __syncthreads();                      // os complete; xs consumed

        // ---- coalesced store: 128 threads x 1 float4 = 64 rows x 8 q ----
        if (t < 128) {
            int row = t >> 1, c = t & 1;
            float4 o = *(const float4*)&os[row * OSS + c * 4];
            int r = rbase + tile * TROWS + row;
            if (r < B)
                *(float4*)(out + (size_t)r * Q + qb + c * 4) = o;
        }

        if (tile + 1 < NTILE) STAGE(tile + 1) // next-tile stage (barrier-protected)
    }
#undef STAGE
#undef EL2
#undef COMP
}

extern "C" void kernel_launch(void* const* d_in, const int* in_sizes, int n_in,
                              void* d_out, int out_size, void* d_ws, size_t ws_size,
                              hipStream_t stream) {
    const float* x  = (const float*)d_in[0];
    const float* W1 = (const float*)d_in[1];
    const float* b1 = (const float*)d_in[2];
    const float* W2 = (const float*)d_in[3];
    const float* b2 = (const float*)d_in[4];
    float* out = (float*)d_out;

    unsigned short* W1T = (unsigned short*)d_ws;                 // 64 KB
    float*          b1F = (float*)((char*)d_ws + 65536);         // 16 KB
    float*          w2F = (float*)((char*)d_ws + 81920);         // 16 KB
    float*          b2F = (float*)((char*)d_ws + 98304);         // 512 B

    const int B = in_sizes[0] / (Q * S);
    const int nblocks = ((B + RPB - 1) / RPB) * (Q / QW);   // 64 x 16 = 1024

    hipLaunchKernelGGL(prep_kernel, dim3(Q), dim3(256), 0, stream,
                       W1, b1, W2, b2, W1T, b1F, w2F, b2F);
    hipLaunchKernelGGL(divenc_wreg, dim3(nblocks), dim3(256), 0, stream,
                       x, W1T, b1F, w2F, b2F, out, B);
}

// Round 19
// 82.160 us; speedup vs baseline: 2.9239x; 1.1613x over previous
//
#include <hip/hip_runtime.h>

// B=65536, Q=128, S=8, U=32
// out[b,q] = b2[q] + sum_u elu(b1[q,u] + sum_s x[b,q,s]*W1[q,s,u]) * W2[q,u]
//
// R19 = R18 (weights-in-registers, 95.4us) + T14 split-stage:
//  STAGE had ds_write directly dependent on its own global loads, exposing
//  ~700cy/tile to every wave in lockstep. Split: LOADT (4 global_load_dwordx4
//  -> named regs) issues right after the xs-ready barrier and flies under
//  COMP; WRITET (cvt_pk + ds_write) lands after the os barrier + store.
#define Q    128
#define S    8
#define U    32
#define QW   8              // q per block
#define TROWS 64            // rows per tile
#define RPB  1024           // rows per block
#define NTILE (RPB / TROWS) // 16
#define RSTRIDE 272         // xs row stride bytes (R9-verified conflict-free)
#define ZOFF (TROWS * RSTRIDE)
#define OSS  20             // os row stride floats (R17 pattern)

typedef __attribute__((ext_vector_type(8)))  __bf16 bf16x8;
typedef __attribute__((ext_vector_type(16))) float  f32x16;
typedef __attribute__((ext_vector_type(2)))  float  f32x2;

__device__ inline unsigned short f2bf(float f) {   // RTN f32->bf16 (prep only)
    unsigned int u = __float_as_uint(f);
    u += 0x7FFF + ((u >> 16) & 1);
    return (unsigned short)(u >> 16);
}

__device__ inline unsigned int cvt_pk_bf16(float lo, float hi) {
    unsigned int r;
    asm("v_cvt_pk_bf16_f32 %0, %1, %2" : "=v"(r) : "v"(lo), "v"(hi));
    return r;
}

// ---- prep: W1T[q][u][s] bf16 ; b1F=(b1+1), w2F in C-reg order ; b2F=b2-sum(W2)
__global__ void prep_kernel(const float* __restrict__ W1, const float* __restrict__ b1,
                            const float* __restrict__ W2, const float* __restrict__ b2,
                            unsigned short* __restrict__ W1T,
                            float* __restrict__ b1F, float* __restrict__ w2F,
                            float* __restrict__ b2F)
{
    const int q = blockIdx.x, t = threadIdx.x;     // 128 blocks x 256 threads
    const int u = t & 31, s = t >> 5;
    W1T[(q * 32 + u) * 8 + s] = f2bf(W1[(q * 8 + s) * 32 + u]);
    if (t < 32) {
        int reg = t & 15, hh = t >> 4;
        int uu  = (reg & 3) + 8 * (reg >> 2) + 4 * hh;   // verified C/D row map
        b1F[(q * 2 + hh) * 16 + reg] = b1[q * 32 + uu] + 1.0f;
        w2F[(q * 2 + hh) * 16 + reg] = W2[q * 32 + uu];
    }
    if (t == 0) {
        float sw = 0.f;
        for (int uu = 0; uu < 32; ++uu) sw += W2[q * 32 + uu];
        b2F[q] = b2[q] - sw;
    }
}

__global__ __launch_bounds__(256)
__attribute__((amdgpu_waves_per_eu(3, 4)))   // budget ~170: resident weights must not spill
void divenc_wreg(const float* __restrict__ x,
                 const unsigned short* __restrict__ W1T,
                 const float* __restrict__ b1F,
                 const float* __restrict__ w2F,
                 const float* __restrict__ b2F,
                 float* __restrict__ out, int B)
{
    __shared__ __align__(16) unsigned char xs[TROWS * RSTRIDE + 16];  // 17.4 KB
    __shared__ __align__(16) float os[TROWS * OSS];                    // 5 KB

    const int t    = threadIdx.x;
    const int lane = t & 63;
    const int wv   = __builtin_amdgcn_readfirstlane(t >> 6);
    const int bl   = lane & 31;
    const int h    = lane >> 5;
    const bool lo  = (lane < 32);

    const int bid   = blockIdx.x;
    const int qb    = (bid & 15) * QW;
    const int rbase = (bid >> 4) * RPB;
    const int rmax  = B - 1;

    if (t == 0) *(uint4*)(xs + ZOFF) = uint4{0, 0, 0, 0};   // zero page

    // ---- resident weights: wave wv owns qA, qB for the whole block ----
    const int qA = qb + wv * 2, qB = qA + 1;
    const uint4  axA  = *(const uint4*)(W1T + ((size_t)qA * 32 + bl) * 8);
    const uint4  axB  = *(const uint4*)(W1T + ((size_t)qB * 32 + bl) * 8);
    const f32x16 cinA = *(const f32x16*)(b1F + ((size_t)qA * 2 + h) * 16);
    const f32x16 cinB = *(const f32x16*)(b1F + ((size_t)qB * 2 + h) * 16);
    const f32x16 wrA  = *(const f32x16*)(w2F + ((size_t)qA * 2 + h) * 16);
    const f32x16 wrB  = *(const f32x16*)(w2F + ((size_t)qB * 2 + h) * 16);
    const float  b2A  = b2F[qA], b2B = b2F[qB];

    const f32x2 l2e2  = 1.44269504088896f;
    const f32x2 nl2e2 = -1.44269504088896f;
    const f32x2 zero2 = 0.0f;

    // staging geometry (fixed per thread): unit k covers (rowk, qrk)
    const int row0 = t >> 3,          qr0 = t & 7;          // unit t
    const int row1 = (t + 256) >> 3,  qr1 = t & 7;          // unit t+256
    float4 pa0, pb0, pa1, pb1;                              // in-flight tile data

#define LOADT(T) {                                                                   \
    int r0_ = rbase + (T) * TROWS + row0; if (r0_ > rmax) r0_ = rmax;                \
    int r1_ = rbase + (T) * TROWS + row1; if (r1_ > rmax) r1_ = rmax;                \
    const float4* p0_ = (const float4*)(x + (size_t)r0_ * (Q * S)                    \
                                          + (size_t)(qb + qr0) * S);                 \
    const float4* p1_ = (const float4*)(x + (size_t)r1_ * (Q * S)                    \
                                          + (size_t)(qb + qr1) * S);                 \
    pa0 = p0_[0]; pb0 = p0_[1];                                                      \
    pa1 = p1_[0]; pb1 = p1_[1]; }

#define WRITET() {                                                                   \
    uint4 w0_, w1_;                                                                  \
    w0_.x = cvt_pk_bf16(pa0.x, pa0.y); w0_.y = cvt_pk_bf16(pa0.z, pa0.w);            \
    w0_.z = cvt_pk_bf16(pb0.x, pb0.y); w0_.w = cvt_pk_bf16(pb0.z, pb0.w);            \
    w1_.x = cvt_pk_bf16(pa1.x, pa1.y); w1_.y = cvt_pk_bf16(pa1.z, pa1.w);            \
    w1_.z = cvt_pk_bf16(pb1.x, pb1.y); w1_.w = cvt_pk_bf16(pb1.z, pb1.w);            \
    *(uint4*)(xs + row0 * RSTRIDE + qr0 * 16) = w0_;                                 \
    *(uint4*)(xs + row1 * RSTRIDE + qr1 * 16) = w1_; }

#define EL2(CC, J, WR, ACC) {                                                        \
    f32x2 v_; v_.x = CC[2*(J)]; v_.y = CC[2*(J)+1];                                  \
    f32x2 w2v; w2v.x = WR[2*(J)]; w2v.y = WR[2*(J)+1];                               \
    f32x2 f_ = __builtin_elementwise_fma(v_, l2e2, nl2e2);                           \
    f_ = __builtin_elementwise_min(f_, zero2);                                       \
    f32x2 e_; e_.x = __builtin_amdgcn_exp2f(f_.x);                                   \
    e_.y = __builtin_amdgcn_exp2f(f_.y);                                             \
    f32x2 r_ = __builtin_elementwise_max(v_, e_);                                    \
    ACC = __builtin_elementwise_fma(r_, w2v, ACC); }

#define COMP(AX, CIN, WR, B2, QR) {                                                  \
    const int xoff = bl * RSTRIDE + (QR) * 16;                                       \
    uint4 bx0 = *(const uint4*)(xs + (lo ? xoff                : ZOFF));             \
    uint4 bx1 = *(const uint4*)(xs + (lo ? xoff + 32 * RSTRIDE : ZOFF));             \
    f32x16 cc0 = __builtin_amdgcn_mfma_f32_32x32x16_bf16(                            \
        __builtin_bit_cast(bf16x8, AX), __builtin_bit_cast(bf16x8, bx0),             \
        CIN, 0, 0, 0);                                                               \
    f32x16 cc1 = __builtin_amdgcn_mfma_f32_32x32x16_bf16(                            \
        __builtin_bit_cast(bf16x8, AX), __builtin_bit_cast(bf16x8, bx1),             \
        CIN, 0, 0, 0);                                                               \
    f32x2 acc0 = 0.0f, acc1 = 0.0f;                                                  \
    EL2(cc0, 0, WR, acc0) EL2(cc0, 1, WR, acc0) EL2(cc0, 2, WR, acc0)                \
    EL2(cc0, 3, WR, acc0) EL2(cc0, 4, WR, acc0) EL2(cc0, 5, WR, acc0)                \
    EL2(cc0, 6, WR, acc0) EL2(cc0, 7, WR, acc0)                                      \
    EL2(cc1, 0, WR, acc1) EL2(cc1, 1, WR, acc1) EL2(cc1, 2, WR, acc1)                \
    EL2(cc1, 3, WR, acc1) EL2(cc1, 4, WR, acc1) EL2(cc1, 5, WR, acc1)                \
    EL2(cc1, 6, WR, acc1) EL2(cc1, 7, WR, acc1)                                      \
    float a0 = acc0.x + acc0.y;                                                      \
    float a1 = acc1.x + acc1.y;                                                      \
    a0 += __shfl_xor(a0, 32);                 /* combine u-halves */                 \
    a1 += __shfl_xor(a1, 32);                                                        \
    if (lo) {                                                                        \
        os[bl * OSS + (QR)]        = a0 + (B2);                                      \
        os[(bl + 32) * OSS + (QR)] = a1 + (B2);                                      \
    } }

    // ---- prologue: tile 0 staged serially (once) ----
    LOADT(0) WRITET()

    #pragma unroll 1
    for (int tile = 0; tile < NTILE; ++tile) {
        __syncthreads();                      // xs[tile] ready; os free

        if (tile + 1 < NTILE) LOADT(tile + 1) // T14: issue early, fly under COMP

        COMP(axA, cinA, wrA, b2A, wv * 2)     // zero weight VMEM in the loop
        COMP(axB, cinB, wrB, b2B, wv * 2 + 1)

        __syncthreads();                      // os complete; xs consumed

        // ---- coalesced store: 128 threads x 1 float4 = 64 rows x 8 q ----
        if (t < 128) {
            int row = t >> 1, c = t & 1;
            float4 o = *(const float4*)&os[row * OSS + c * 4];
            int r = rbase + tile * TROWS + row;
            if (r < B)
                *(float4*)(out + (size_t)r * Q + qb + c * 4) = o;
        }

        if (tile + 1 < NTILE) WRITET()        // T14: write late (loads landed)
    }
#undef LOADT
#undef WRITET
#undef EL2
#undef COMP
}

extern "C" void kernel_launch(void* const* d_in, const int* in_sizes, int n_in,
                              void* d_out, int out_size, void* d_ws, size_t ws_size,
                              hipStream_t stream) {
    const float* x  = (const float*)d_in[0];
    const float* W1 = (const float*)d_in[1];
    const float* b1 = (const float*)d_in[2];
    const float* W2 = (const float*)d_in[3];
    const float* b2 = (const float*)d_in[4];
    float* out = (float*)d_out;

    unsigned short* W1T = (unsigned short*)d_ws;                 // 64 KB
    float*          b1F = (float*)((char*)d_ws + 65536);         // 16 KB
    float*          w2F = (float*)((char*)d_ws + 81920);         // 16 KB
    float*          b2F = (float*)((char*)d_ws + 98304);         // 512 B

    const int B = in_sizes[0] / (Q * S);
    const int nblocks = ((B + RPB - 1) / RPB) * (Q / QW);   // 64 x 16 = 1024

    hipLaunchKernelGGL(prep_kernel, dim3(Q), dim3(256), 0, stream,
                       W1, b1, W2, b2, W1T, b1F, w2F, b2F);
    hipLaunchKernelGGL(divenc_wreg, dim3(nblocks), dim3(256), 0, stream,
                       x, W1T, b1F, w2F, b2F, out, B);
}